// Round 2
// baseline (185.584 us; speedup 1.0000x reference)
//
#include <hip/hip_runtime.h>

// ComboSumModule: six independent sum-over-axis-1 reductions (f32).
// Shapes: (2048,128,64) (2048,32,32) (2048,64,64) (2048,16,48)
//         (2048,200,32) (2048,8,8). Outputs concatenated flat (f32).
//
// R7 theory: R4/R5 (2.75 TB/s app, 19 waves/CU, shallow MLP) and R6
// (2.36 TB/s, 8 waves/CU, deep MLP) show throughput = waves x per-wave
// rate, never both levers at once. R7: (a) contiguous slab streaming --
// one wave owns one batch slab (lane column invariant since 64%N4==0),
// wave-loads are single 1KB contiguous segments like the 6.3TB/s copy
// ubench; (b) full residency -- 7104 waves, launch_bounds(256,8) forces
// VGPR<=64 -> 32 waves/CU capacity, whole grid co-resident; (c) rolling
// 8-deep pipeline (t=v[j]; v[j]=reload; acc+=t) whose WAR dependence
// forces vmcnt(7) partial waits -- 8 loads always in flight per wave.
// No LDS, no barriers anywhere.
// Predicted: occupancy 25->75-95%, dur 68->~30-40us if latency-bound
// theory right; if dur >=55us at high occupancy, ~2.7 TB/s is a real
// service ceiling for this pattern (3 distinct structures agree).

__device__ __forceinline__ float4 f4add(float4 a, float4 b) {
  return make_float4(a.x + b.x, a.y + b.y, a.z + b.z, a.w + b.w);
}

__device__ __forceinline__ float4 f4zero() {
  return make_float4(0.f, 0.f, 0.f, 0.f);
}

__device__ __forceinline__ float4 shfl_xor_add(float4 r, int off) {
  r.x += __shfl_xor(r.x, off);
  r.y += __shfl_xor(r.y, off);
  r.z += __shfl_xor(r.z, off);
  r.w += __shfl_xor(r.w, off);
  return r;
}

// Rolling pipeline: LOADS float4 loads at stride STRIDE4, PIPE in flight.
// Copy-out before reload: the reload's WAR on v[j] keeps program order
// (add then reload) while the compiler's waitcnt is only vmcnt(PIPE-1).
template <int LOADS, int STRIDE4, int PIPE>
__device__ __forceinline__ float4 roll_sum(const float4* __restrict__ p) {
  constexpr int P = (LOADS < PIPE) ? LOADS : PIPE;
  float4 v[P];
  float4 a0 = f4zero(), a1 = f4zero();
#pragma unroll
  for (int i = 0; i < P; ++i) v[i] = p[(size_t)i * STRIDE4];
#pragma unroll
  for (int k = 0; k < LOADS - P; ++k) {
    float4 t = v[k % P];
    v[k % P] = p[(size_t)(k + P) * STRIDE4];
    if (k & 1) a1 = f4add(a1, t);
    else a0 = f4add(a0, t);
  }
#pragma unroll
  for (int k = LOADS - P; k < LOADS; ++k) {
    if (k & 1) a1 = f4add(a1, v[k % P]);
    else a0 = f4add(a0, v[k % P]);
  }
  return f4add(a0, a1);
}

// One wave sums one whole batch slab (M*N4 float4s, contiguous).
// Lane reads f4 index f = i*64+lane; since 64%N4==0, lane's column is
// constant (lane & (N4-1)); row-group = lane/N4 covers rows r == lane/N4
// (mod 64/N4). shfl_xor over {N4..32} combines groups; lanes<N4 store.
template <int M, int N4>
__device__ __forceinline__ void slab_sum(const float* __restrict__ xp,
                                         float4* __restrict__ outp, int b,
                                         int lane) {
  constexpr int L = M * N4 / 64;
  const float4* p =
      reinterpret_cast<const float4*>(xp) + (size_t)b * (M * N4) + lane;
  float4 r = roll_sum<L, 64, 8>(p);
#pragma unroll
  for (int off = N4; off < 64; off <<= 1) r = shfl_xor_add(r, off);
  if (lane < N4) outp[(size_t)b * N4 + lane] = r;
}

// x1 (M=32,N4=8): slab is only 4KB, so one wave streams 4 consecutive
// batches (16 contiguous 1KB loads); acc index = load/4 (static under
// unroll -> stays in registers).
__device__ __forceinline__ void x1_quad(const float* __restrict__ xp,
                                        float4* __restrict__ outp, int w,
                                        int lane) {
  const int b0 = w << 2;
  const float4* p =
      reinterpret_cast<const float4*>(xp) + (size_t)b0 * 256 + lane;
  float4 v[8];
  float4 acc[4] = {f4zero(), f4zero(), f4zero(), f4zero()};
#pragma unroll
  for (int i = 0; i < 8; ++i) v[i] = p[(size_t)i * 64];
#pragma unroll
  for (int k = 0; k < 8; ++k) {
    float4 t = v[k];
    v[k] = p[(size_t)(k + 8) * 64];
    acc[k >> 2] = f4add(acc[k >> 2], t);
  }
#pragma unroll
  for (int k = 8; k < 16; ++k) acc[k >> 2] = f4add(acc[k >> 2], v[k - 8]);
#pragma unroll
  for (int j = 0; j < 4; ++j) {
    float4 r = acc[j];
    r = shfl_xor_add(r, 8);
    r = shfl_xor_add(r, 16);
    r = shfl_xor_add(r, 32);
    if (lane < 8) outp[(size_t)(b0 + j) * 8 + lane] = r;
  }
}

// Column-walk fallback for tensors where 64%N4 != 0 (x3) or slabs are
// tiny (x5): lane owns output unit u, walks M rows at stride N4.
template <int M, int N4>
__device__ __forceinline__ void col_walk(const float* __restrict__ xp,
                                         float4* __restrict__ outp, int task,
                                         int lane) {
  const int u = task * 64 + lane;
  const int b = u / N4;  // const divisor -> magic-mul
  const int n4 = u - b * N4;
  const float4* p =
      reinterpret_cast<const float4*>(xp) + (size_t)b * (M * N4) + n4;
  outp[u] = roll_sum<M, N4, 8>(p);
}

// Wave map (4 waves/block, all region boundaries block-uniform):
//   blk [   0, 512): x0 M=128 N4=16, 1 batch/wave  (32 loads, 32KB)
//   blk [ 512,1024): x4 M=200 N4= 8, 1 batch/wave  (25 loads, 25KB)
//   blk [1024,1536): x2 M= 64 N4=16, 1 batch/wave  (16 loads, 16KB)
//   blk [1536,1664): x1 M= 32 N4= 8, 4 batches/wave(16 loads, 16KB)
//   blk [1664,1760): x3 col-walk    (16 loads/lane, 16KB/wave)
//   blk [1760,1776): x5 col-walk    ( 8 loads/lane,  8KB/wave)
// Output float4 bases: x0 0, x1 32768, x2 49152, x3 81920, x4 106496,
// x5 122880.
__global__ __launch_bounds__(256, 8) void ComboSumModule_25314537242674_kernel(
    const float* __restrict__ x0, const float* __restrict__ x1,
    const float* __restrict__ x2, const float* __restrict__ x3,
    const float* __restrict__ x4, const float* __restrict__ x5,
    float* __restrict__ out) {
  const int lane = threadIdx.x & 63;
  const int wave = threadIdx.x >> 6;
  const int blk = blockIdx.x;
  float4* out4 = reinterpret_cast<float4*>(out);

  if (blk < 512) {
    slab_sum<128, 16>(x0, out4 + 0, (blk << 2) | wave, lane);
  } else if (blk < 1024) {
    slab_sum<200, 8>(x4, out4 + 106496, ((blk - 512) << 2) | wave, lane);
  } else if (blk < 1536) {
    slab_sum<64, 16>(x2, out4 + 49152, ((blk - 1024) << 2) | wave, lane);
  } else if (blk < 1664) {
    x1_quad(x1, out4 + 32768, ((blk - 1536) << 2) | wave, lane);
  } else if (blk < 1760) {
    col_walk<16, 12>(x3, out4 + 81920, ((blk - 1664) << 2) | wave, lane);
  } else {
    col_walk<8, 2>(x5, out4 + 122880, ((blk - 1760) << 2) | wave, lane);
  }
}

extern "C" void kernel_launch(void* const* d_in, const int* in_sizes, int n_in,
                              void* d_out, int out_size, void* d_ws,
                              size_t ws_size, hipStream_t stream) {
  const float* x0 = (const float*)d_in[0];
  const float* x1 = (const float*)d_in[1];
  const float* x2 = (const float*)d_in[2];
  const float* x3 = (const float*)d_in[3];
  const float* x4 = (const float*)d_in[4];
  const float* x5 = (const float*)d_in[5];
  // d_in[6] is the python scalar dim=1; reduction axis baked in.
  float* out = (float*)d_out;

  ComboSumModule_25314537242674_kernel<<<1776, 256, 0, stream>>>(x0, x1, x2,
                                                                 x3, x4, x5,
                                                                 out);
}

// Round 3
// 169.293 us; speedup vs baseline: 1.0962x; 1.0962x over previous
//
#include <hip/hip_runtime.h>

// ComboSumModule: six independent sum-over-axis-1 reductions (f32).
// Shapes: (2048,128,64) (2048,32,32) (2048,64,64) (2048,16,48)
//         (2048,200,32) (2048,8,8). Outputs concatenated flat.
//
// R8: R4/R6/R7 (three structurally distinct kernels: 16-wave+LDS, 4-wave
// deep-MLP, full-residency contiguous slabs) all saturate at ~2.4-2.8 TB/s
// app-level reads with every pipe idle (VALUBusy<2%, HBM 18%, occ 25-60%).
// In-flight bytes (~14MB chip-wide) >> BDP (~3MB @6.3TB/s,500ns) => the
// regime is service-rate-limited, not latency-limited; per-wave MLP and
// residency are NOT the levers. rocprof replay passes with inputs fully
// L3-resident (hbm_gbps~68) ran at the SAME duration => the ~2.5TB/s cap
// sits on the shared L2-miss/Infinity-Fabric read path, independent of
// data source. Last untested lever on that path: non-temporal loads.
// R8 = R5's kernel (best known, 58.4us/dispatch) with all input loads
// nt-hinted; nothing else changed.
// Predicted if theory right: FETCH_SIZE 82MB -> ~160MB, hbm_gbps 1.4 ->
// 3.5-5 TB/s, dur 58 -> 35-45us. If dur 58+-3us: pattern ceiling is real,
// declare roofline next round.

typedef float f32x4 __attribute__((ext_vector_type(4)));

__device__ __forceinline__ float4 ntload(const float4* __restrict__ p) {
  f32x4 v = __builtin_nontemporal_load(reinterpret_cast<const f32x4*>(p));
  return make_float4(v.x, v.y, v.z, v.w);
}

__device__ __forceinline__ float4 f4add(float4 a, float4 b) {
  return make_float4(a.x + b.x, a.y + b.y, a.z + b.z, a.w + b.w);
}

// Per-wave partial: sum CNT rows starting at row_start for this lane's
// output unit. All CNT loads issued before any add; reverse-order
// consumption pins all CNT float4 buffers live (forces full MLP).
template <int M, int N, int CNT>
__device__ __forceinline__ float4 partial(const float* __restrict__ xp,
                                          int group, int row_start, int lane) {
  constexpr int N4 = N / 4;
  const int u = group * 64 + lane;   // unit index local to tensor
  const int b = u / N4;              // const divisor -> magic-mul
  const int n4 = u - b * N4;
  const float4* __restrict__ p =
      reinterpret_cast<const float4*>(xp) + (size_t)b * (M * N4) +
      (size_t)row_start * N4 + n4;

  float4 v[CNT];
#pragma unroll
  for (int i = 0; i < CNT; ++i) v[i] = ntload(p + (size_t)i * N4);

  // Reverse order: first add needs the LAST load -> compiler cannot hoist
  // any add above any load; all CNT buffers stay live.
  float4 r = v[CNT - 1];
#pragma unroll
  for (int i = CNT - 2; i >= 0; --i) r = f4add(r, v[i]);
  return r;
}

// Combine WPG per-wave partials for a 64-unit group via LDS; lead wave
// stores. WPG==1 stores directly. Barrier reached by all 16 waves.
template <int WPG>
__device__ __forceinline__ void combine(float4 r, float* __restrict__ out,
                                        int out_base4, int group, int wave,
                                        int lane, float4* lds) {
  if (WPG == 1) {
    reinterpret_cast<float4*>(out)[out_base4 + group * 64 + lane] = r;
    return;
  }
  lds[wave * 64 + lane] = r;
  __syncthreads();
  if ((wave & (WPG - 1)) == 0) {
    float4 s = lds[wave * 64 + lane];
#pragma unroll
    for (int j = 1; j < WPG; ++j) s = f4add(s, lds[(wave + j) * 64 + lane]);
    reinterpret_cast<float4*>(out)[out_base4 + group * 64 + lane] = s;
  }
}

// Block order (heaviest first): x4 [0,256) x0 [256,768) x2 [768,1024)
// x1 [1024,1088) x3 [1088,1136) x5 [1136,1140). Region branch is
// block-uniform; only x4's CNT differs per wave (barrier outside).
__global__ __launch_bounds__(1024) void ComboSumModule_25314537242674_kernel(
    const float* __restrict__ x0, const float* __restrict__ x1,
    const float* __restrict__ x2, const float* __restrict__ x3,
    const float* __restrict__ x4, const float* __restrict__ x5,
    float* __restrict__ out) {
  __shared__ float4 lds[16 * 64];  // 16 KB
  const int lane = threadIdx.x & 63;
  const int wave = threadIdx.x >> 6;
  const int blk = blockIdx.x;

  if (blk < 256) {
    // x4: M=200 N=32, 1 group/block; waves 0-7: 13 rows, waves 8-15: 12.
    float4 r;
    if (wave < 8)
      r = partial<200, 32, 13>(x4, blk, 13 * wave, lane);
    else
      r = partial<200, 32, 12>(x4, blk, 104 + 12 * (wave - 8), lane);
    combine<16>(r, out, 106496, blk, wave, lane, lds);
  } else if (blk < 768) {
    // x0: M=128 N=64, 1 group/block, wave w rows [8w, 8w+8).
    float4 r = partial<128, 64, 8>(x0, blk - 256, 8 * wave, lane);
    combine<16>(r, out, 0, blk - 256, wave, lane, lds);
  } else if (blk < 1024) {
    // x2: M=64 N=64, 2 groups/block, 8 waves each.
    const int g = (blk - 768) * 2 + (wave >> 3);
    float4 r = partial<64, 64, 8>(x2, g, 8 * (wave & 7), lane);
    combine<8>(r, out, 49152, g, wave, lane, lds);
  } else if (blk < 1088) {
    // x1: M=32 N=32, 4 groups/block, 4 waves each.
    const int g = (blk - 1024) * 4 + (wave >> 2);
    float4 r = partial<32, 32, 8>(x1, g, 8 * (wave & 3), lane);
    combine<4>(r, out, 32768, g, wave, lane, lds);
  } else if (blk < 1136) {
    // x3: M=16 N=48, 8 groups/block, 2 waves each.
    const int g = (blk - 1088) * 8 + (wave >> 1);
    float4 r = partial<16, 48, 8>(x3, g, 8 * (wave & 1), lane);
    combine<2>(r, out, 81920, g, wave, lane, lds);
  } else {
    // x5: M=8 N=8, 16 groups/block, 1 wave each, direct store.
    const int g = (blk - 1136) * 16 + wave;
    float4 r = partial<8, 8, 8>(x5, g, 0, lane);
    combine<1>(r, out, 122880, g, wave, lane, lds);
  }
}

extern "C" void kernel_launch(void* const* d_in, const int* in_sizes, int n_in,
                              void* d_out, int out_size, void* d_ws, size_t ws_size,
                              hipStream_t stream) {
  const float* x0 = (const float*)d_in[0];
  const float* x1 = (const float*)d_in[1];
  const float* x2 = (const float*)d_in[2];
  const float* x3 = (const float*)d_in[3];
  const float* x4 = (const float*)d_in[4];
  const float* x5 = (const float*)d_in[5];
  // d_in[6] is the python scalar dim=1; reduction axis baked in.
  float* out = (float*)d_out;

  ComboSumModule_25314537242674_kernel<<<1140, 1024, 0, stream>>>(
      x0, x1, x2, x3, x4, x5, out);
}